// Round 1
// baseline (532.885 us; speedup 1.0000x reference)
//
#include <hip/hip_runtime.h>

typedef __bf16 bf16x8 __attribute__((ext_vector_type(8)));
typedef float f32x4 __attribute__((ext_vector_type(4)));

#define MFMA16(a, b, c) __builtin_amdgcn_mfma_f32_16x16x32_bf16((a), (b), (c), 0, 0, 0)

__device__ __forceinline__ unsigned short f2bf(float f) {
    union { float f; unsigned int u; } v;
    v.f = f;
    unsigned int r = v.u + 0x7fffu + ((v.u >> 16) & 1u);
    return (unsigned short)(r >> 16);
}

// ---------------------------------------------------------------------------
// Convert the four 256x256 fp32 weight matrices to bf16.
__global__ __launch_bounds__(256) void cvt_weights(
    const float* __restrict__ Wq, const float* __restrict__ Wk,
    const float* __restrict__ Wv, const float* __restrict__ Wp,
    unsigned short* __restrict__ out)
{
    int i = blockIdx.x * 256 + threadIdx.x;  // 0..65535
    out[i]          = f2bf(Wq[i]);
    out[65536 + i]  = f2bf(Wk[i]);
    out[131072 + i] = f2bf(Wv[i]);
    out[196608 + i] = f2bf(Wp[i]);
}

// ---------------------------------------------------------------------------
// Q & K projection fused: q = (x+pe) @ Wq^T + bq ; k = (x+pe) @ Wk^T + bk
// Tile: 64(M tokens) x 64(N outch), BK=32. Block=256 thr=4 waves (2x2 of 32x32).
__global__ __launch_bounds__(256) void qk_gemm(
    const float* __restrict__ x,
    const unsigned short* __restrict__ Wq,
    const unsigned short* __restrict__ Wk,
    const float* __restrict__ bq,
    const float* __restrict__ bk,
    unsigned short* __restrict__ qo,
    unsigned short* __restrict__ ko)
{
    __shared__ unsigned short As[64 * 40];
    __shared__ unsigned short Bq[64 * 40];
    __shared__ unsigned short Bk[64 * 40];
    __shared__ float petab[8 * 256];  // [coord 0..7][channel]

    const int tid = threadIdx.x;
    const int m0 = blockIdx.x * 64;
    const int n0 = blockIdx.y * 64;

    // PE table: pe(v,c) = sin/cos(3.14 * v * f * 0.005), f = c&63, cos if c&64.
    #pragma unroll
    for (int t = 0; t < 8; ++t) {
        int idx = t * 256 + tid;
        int v = idx >> 8;
        int c = idx & 255;
        float ang = 0.0157f * (float)v * (float)(c & 63);
        petab[idx] = (c & 64) ? __cosf(ang) : __sinf(ang);
    }
    __syncthreads();

    const int lane = tid & 63;
    const int wid = tid >> 6;
    const int quad = lane >> 4;
    const int l15 = lane & 15;
    const int m_off = (wid >> 1) * 32;
    const int n_off = (wid & 1) * 32;

    const int srow = tid >> 2;        // 0..63
    const int scol = (tid & 3) * 8;   // 0,8,16,24
    const int tok = m0 + srow;
    const int tx = tok & 7;
    const int ty = (tok >> 7) & 7;
    const float* xrow = x + (size_t)tok * 256;

    f32x4 zero4 = {0.f, 0.f, 0.f, 0.f};
    f32x4 aq[2][2], ak[2][2];
    #pragma unroll
    for (int i = 0; i < 2; ++i)
        #pragma unroll
        for (int j = 0; j < 2; ++j) { aq[i][j] = zero4; ak[i][j] = zero4; }

    for (int k0 = 0; k0 < 256; k0 += 32) {
        float4 f0 = *(const float4*)(xrow + k0 + scol);
        float4 f1 = *(const float4*)(xrow + k0 + scol + 4);
        float xv[8] = {f0.x, f0.y, f0.z, f0.w, f1.x, f1.y, f1.z, f1.w};
        const int cbase = k0 + scol;
        const float* pt = petab + ((cbase < 128) ? tx : ty) * 256 + cbase;
        alignas(16) unsigned short st[8];
        #pragma unroll
        for (int j = 0; j < 8; ++j) st[j] = f2bf(xv[j] + pt[j]);
        *(uint4*)&As[srow * 40 + scol] = *(const uint4*)st;
        *(uint4*)&Bq[srow * 40 + scol] = *(const uint4*)&Wq[(size_t)(n0 + srow) * 256 + k0 + scol];
        *(uint4*)&Bk[srow * 40 + scol] = *(const uint4*)&Wk[(size_t)(n0 + srow) * 256 + k0 + scol];
        __syncthreads();

        bf16x8 af[2], bqf[2], bkf[2];
        #pragma unroll
        for (int i = 0; i < 2; ++i) {
            af[i]  = *(const bf16x8*)&As[(m_off + i * 16 + l15) * 40 + quad * 8];
            bqf[i] = *(const bf16x8*)&Bq[(n_off + i * 16 + l15) * 40 + quad * 8];
            bkf[i] = *(const bf16x8*)&Bk[(n_off + i * 16 + l15) * 40 + quad * 8];
        }
        #pragma unroll
        for (int i = 0; i < 2; ++i)
            #pragma unroll
            for (int j = 0; j < 2; ++j) {
                aq[i][j] = MFMA16(af[i], bqf[j], aq[i][j]);
                ak[i][j] = MFMA16(af[i], bkf[j], ak[i][j]);
            }
        __syncthreads();
    }

    #pragma unroll
    for (int j = 0; j < 2; ++j) {
        const int n = n0 + n_off + j * 16 + l15;
        const float bqv = bq[n];
        const float bkv = bk[n];
        #pragma unroll
        for (int i = 0; i < 2; ++i) {
            #pragma unroll
            for (int r = 0; r < 4; ++r) {
                const int m = m0 + m_off + i * 16 + quad * 4 + r;
                qo[(size_t)m * 256 + n] = f2bf(aq[i][j][r] + bqv);
                ko[(size_t)m * 256 + n] = f2bf(ak[i][j][r] + bkv);
            }
        }
    }
}

// ---------------------------------------------------------------------------
// V projection, stored transposed per window: vt[g][c][tok] = x_g[tok]·Wv[c] + bv[c]
// D[m=c][n=tok] = Wv · x_g^T. Both operands K-contiguous in memory.
__global__ __launch_bounds__(256) void v_gemm(
    const float* __restrict__ x,
    const unsigned short* __restrict__ Wv,
    const float* __restrict__ bv,
    unsigned short* __restrict__ vt)
{
    __shared__ unsigned short Ws[64 * 40];
    __shared__ unsigned short Xs[64 * 40];

    const int tid = threadIdx.x;
    const int g = blockIdx.x;          // window 0..2047
    const int c0 = blockIdx.y * 64;    // output-channel tile
    const int b = g >> 8, wy = (g >> 4) & 15, wx = g & 15;
    const int rowbase = b * 16384 + wy * 1024 + wx * 8;

    const int lane = tid & 63, wid = tid >> 6, quad = lane >> 4, l15 = lane & 15;
    const int m_off = (wid >> 1) * 32, n_off = (wid & 1) * 32;
    const int srow = tid >> 2, scol = (tid & 3) * 8;
    const int trow = rowbase + (srow >> 3) * 128 + (srow & 7);
    const float* xrow = x + (size_t)trow * 256;

    f32x4 zero4 = {0.f, 0.f, 0.f, 0.f};
    f32x4 acc[2][2];
    #pragma unroll
    for (int i = 0; i < 2; ++i)
        #pragma unroll
        for (int j = 0; j < 2; ++j) acc[i][j] = zero4;

    for (int k0 = 0; k0 < 256; k0 += 32) {
        *(uint4*)&Ws[srow * 40 + scol] = *(const uint4*)&Wv[(size_t)(c0 + srow) * 256 + k0 + scol];
        float4 f0 = *(const float4*)(xrow + k0 + scol);
        float4 f1 = *(const float4*)(xrow + k0 + scol + 4);
        float xv[8] = {f0.x, f0.y, f0.z, f0.w, f1.x, f1.y, f1.z, f1.w};
        alignas(16) unsigned short st[8];
        #pragma unroll
        for (int j = 0; j < 8; ++j) st[j] = f2bf(xv[j]);
        *(uint4*)&Xs[srow * 40 + scol] = *(const uint4*)st;
        __syncthreads();

        bf16x8 af[2], bf[2];
        #pragma unroll
        for (int i = 0; i < 2; ++i) {
            af[i] = *(const bf16x8*)&Ws[(m_off + i * 16 + l15) * 40 + quad * 8];
            bf[i] = *(const bf16x8*)&Xs[(n_off + i * 16 + l15) * 40 + quad * 8];
        }
        #pragma unroll
        for (int i = 0; i < 2; ++i)
            #pragma unroll
            for (int j = 0; j < 2; ++j)
                acc[i][j] = MFMA16(af[i], bf[j], acc[i][j]);
        __syncthreads();
    }

    #pragma unroll
    for (int i = 0; i < 2; ++i) {
        #pragma unroll
        for (int r = 0; r < 4; ++r) {
            const int c = c0 + m_off + i * 16 + quad * 4 + r;
            const float bb = bv[c];
            #pragma unroll
            for (int j = 0; j < 2; ++j) {
                const int tokn = n_off + j * 16 + l15;
                vt[(size_t)g * 16384 + (size_t)c * 64 + tokn] = f2bf(acc[i][j][r] + bb);
            }
        }
    }
}

// ---------------------------------------------------------------------------
// Window attention: one wave per (window, head). Q/K/V frags direct from
// global; P (softmax probs) round-trips LDS C-layout -> A-layout.
__global__ __launch_bounds__(256) void attn(
    const unsigned short* __restrict__ q,
    const unsigned short* __restrict__ k,
    const unsigned short* __restrict__ vt,
    unsigned short* __restrict__ o)
{
    __shared__ unsigned short P[4 * 64 * 72];  // per-wave 64x64 probs, pad 72

    const int tid = threadIdx.x;
    const int wid = tid >> 6;
    const int lane = tid & 63;
    const int quad = lane >> 4;
    const int l15 = lane & 15;

    const int wh = blockIdx.x * 4 + wid;   // 0..16383
    const int g = wh >> 3;
    const int h = wh & 7;
    const int b = g >> 8, wy = (g >> 4) & 15, wx = g & 15;
    const int rowbase = b * 16384 + wy * 1024 + wx * 8;

    unsigned short* Pw = P + wid * (64 * 72);
    f32x4 zero4 = {0.f, 0.f, 0.f, 0.f};

    // ---- QK^T: D[p][p'] = sum_d q[p][d] k[p'][d], K=32 = one MFMA.
    bf16x8 aq[4], bk[4];
    #pragma unroll
    for (int t = 0; t < 4; ++t) {
        const int p = t * 16 + l15;
        const int gr = rowbase + ((p >> 3) << 7) + (p & 7);
        aq[t] = *(const bf16x8*)&q[(size_t)gr * 256 + h * 32 + quad * 8];
        bk[t] = *(const bf16x8*)&k[(size_t)gr * 256 + h * 32 + quad * 8];
    }
    f32x4 s[4][4];
    #pragma unroll
    for (int mt = 0; mt < 4; ++mt)
        #pragma unroll
        for (int nt = 0; nt < 4; ++nt)
            s[mt][nt] = MFMA16(aq[mt], bk[nt], zero4);

    // ---- online-free softmax over full rows (row = mt*16 + quad*4 + reg)
    const float KF = 0.17677669529663687f * 1.4426950408889634f;  // scale*log2e
    #pragma unroll
    for (int mt = 0; mt < 4; ++mt) {
        #pragma unroll
        for (int r = 0; r < 4; ++r) {
            float mx = fmaxf(fmaxf(s[mt][0][r], s[mt][1][r]), fmaxf(s[mt][2][r], s[mt][3][r]));
            #pragma unroll
            for (int off = 1; off < 16; off <<= 1) mx = fmaxf(mx, __shfl_xor(mx, off, 16));
            float e[4];
            float sum = 0.f;
            #pragma unroll
            for (int nt = 0; nt < 4; ++nt) { e[nt] = exp2f((s[mt][nt][r] - mx) * KF); sum += e[nt]; }
            #pragma unroll
            for (int off = 1; off < 16; off <<= 1) sum += __shfl_xor(sum, off, 16);
            const float inv = 1.0f / sum;
            const int row = mt * 16 + quad * 4 + r;
            #pragma unroll
            for (int nt = 0; nt < 4; ++nt)
                Pw[row * 72 + nt * 16 + l15] = f2bf(e[nt] * inv);
        }
    }
    __syncthreads();

    // ---- PV: D[p][d] = sum_p' P[p][p'] v[p'][d]; B from vt (k-contiguous).
    f32x4 oa[4][2];
    #pragma unroll
    for (int mt = 0; mt < 4; ++mt) { oa[mt][0] = zero4; oa[mt][1] = zero4; }

    #pragma unroll
    for (int kt = 0; kt < 2; ++kt) {
        bf16x8 ap[4], bv[2];
        #pragma unroll
        for (int mt = 0; mt < 4; ++mt)
            ap[mt] = *(const bf16x8*)&Pw[(mt * 16 + l15) * 72 + kt * 32 + quad * 8];
        #pragma unroll
        for (int nv = 0; nv < 2; ++nv)
            bv[nv] = *(const bf16x8*)&vt[(size_t)g * 16384 +
                                         (size_t)(h * 32 + nv * 16 + l15) * 64 + kt * 32 + quad * 8];
        #pragma unroll
        for (int mt = 0; mt < 4; ++mt)
            #pragma unroll
            for (int nv = 0; nv < 2; ++nv)
                oa[mt][nv] = MFMA16(ap[mt], bv[nv], oa[mt][nv]);
    }

    #pragma unroll
    for (int mt = 0; mt < 4; ++mt) {
        #pragma unroll
        for (int r = 0; r < 4; ++r) {
            const int p = mt * 16 + quad * 4 + r;
            const int gr = rowbase + ((p >> 3) << 7) + (p & 7);
            #pragma unroll
            for (int nv = 0; nv < 2; ++nv)
                o[(size_t)gr * 256 + h * 32 + nv * 16 + l15] = f2bf(oa[mt][nv][r]);
        }
    }
}

// ---------------------------------------------------------------------------
// Output projection: out = o @ Wp^T + bp (fp32 out).
__global__ __launch_bounds__(256) void o_gemm(
    const unsigned short* __restrict__ A,
    const unsigned short* __restrict__ Wp,
    const float* __restrict__ bp,
    float* __restrict__ out)
{
    __shared__ unsigned short As[64 * 40];
    __shared__ unsigned short Bs[64 * 40];

    const int tid = threadIdx.x;
    const int m0 = blockIdx.x * 64;
    const int n0 = blockIdx.y * 64;
    const int lane = tid & 63, wid = tid >> 6, quad = lane >> 4, l15 = lane & 15;
    const int m_off = (wid >> 1) * 32, n_off = (wid & 1) * 32;
    const int srow = tid >> 2, scol = (tid & 3) * 8;

    f32x4 zero4 = {0.f, 0.f, 0.f, 0.f};
    f32x4 acc[2][2];
    #pragma unroll
    for (int i = 0; i < 2; ++i)
        #pragma unroll
        for (int j = 0; j < 2; ++j) acc[i][j] = zero4;

    for (int k0 = 0; k0 < 256; k0 += 32) {
        *(uint4*)&As[srow * 40 + scol] = *(const uint4*)&A[(size_t)(m0 + srow) * 256 + k0 + scol];
        *(uint4*)&Bs[srow * 40 + scol] = *(const uint4*)&Wp[(size_t)(n0 + srow) * 256 + k0 + scol];
        __syncthreads();

        bf16x8 af[2], bf[2];
        #pragma unroll
        for (int i = 0; i < 2; ++i) {
            af[i] = *(const bf16x8*)&As[(m_off + i * 16 + l15) * 40 + quad * 8];
            bf[i] = *(const bf16x8*)&Bs[(n_off + i * 16 + l15) * 40 + quad * 8];
        }
        #pragma unroll
        for (int i = 0; i < 2; ++i)
            #pragma unroll
            for (int j = 0; j < 2; ++j)
                acc[i][j] = MFMA16(af[i], bf[j], acc[i][j]);
        __syncthreads();
    }

    #pragma unroll
    for (int j = 0; j < 2; ++j) {
        const int n = n0 + n_off + j * 16 + l15;
        const float bb = bp[n];
        #pragma unroll
        for (int i = 0; i < 2; ++i) {
            #pragma unroll
            for (int r = 0; r < 4; ++r) {
                const int m = m0 + m_off + i * 16 + quad * 4 + r;
                out[(size_t)m * 256 + n] = acc[i][j][r] + bb;
            }
        }
    }
}

// ---------------------------------------------------------------------------
extern "C" void kernel_launch(void* const* d_in, const int* in_sizes, int n_in,
                              void* d_out, int out_size, void* d_ws, size_t ws_size,
                              hipStream_t stream) {
    const float* x  = (const float*)d_in[0];
    const float* Wq = (const float*)d_in[1];
    const float* bq = (const float*)d_in[2];
    const float* Wk = (const float*)d_in[3];
    const float* bk = (const float*)d_in[4];
    const float* Wv = (const float*)d_in[5];
    const float* bv = (const float*)d_in[6];
    const float* Wp = (const float*)d_in[7];
    const float* bp = (const float*)d_in[8];
    float* out = (float*)d_out;

    char* ws = (char*)d_ws;
    unsigned short* Wbf = (unsigned short*)ws;                 // 4 * 65536 bf16
    unsigned short* qb  = (unsigned short*)(ws + 524288);      // 131072*256 bf16
    unsigned short* kb  = qb + 33554432;
    unsigned short* vtb = kb + 33554432;                        // [2048][256][64]
    unsigned short* ob  = vtb + 33554432;

    cvt_weights<<<256, 256, 0, stream>>>(Wq, Wk, Wv, Wp, Wbf);
    qk_gemm<<<dim3(2048, 4), 256, 0, stream>>>(x, Wbf, Wbf + 65536, bq, bk, qb, kb);
    v_gemm<<<dim3(2048, 4), 256, 0, stream>>>(x, Wbf + 131072, bv, vtb);
    attn<<<4096, 256, 0, stream>>>(qb, kb, vtb, ob);
    o_gemm<<<dim3(2048, 4), 256, 0, stream>>>(ob, Wbf + 196608, bp, out);
}

// Round 2
// 463.191 us; speedup vs baseline: 1.1505x; 1.1505x over previous
//
#include <hip/hip_runtime.h>

typedef __bf16 bf16x8 __attribute__((ext_vector_type(8)));
typedef float f32x4 __attribute__((ext_vector_type(4)));

#define MFMA16(a, b, c) __builtin_amdgcn_mfma_f32_16x16x32_bf16((a), (b), (c), 0, 0, 0)

__device__ __forceinline__ unsigned short f2bf(float f) {
    union { float f; unsigned int u; } v;
    v.f = f;
    unsigned int r = v.u + 0x7fffu + ((v.u >> 16) & 1u);
    return (unsigned short)(r >> 16);
}

// ---------------------------------------------------------------------------
// Convert the four 256x256 fp32 weight matrices to bf16 (q,k,v,p contiguous).
__global__ __launch_bounds__(256) void cvt_weights(
    const float* __restrict__ Wq, const float* __restrict__ Wk,
    const float* __restrict__ Wv, const float* __restrict__ Wp,
    unsigned short* __restrict__ out)
{
    int i = blockIdx.x * 256 + threadIdx.x;  // 0..65535
    out[i]          = f2bf(Wq[i]);
    out[65536 + i]  = f2bf(Wk[i]);
    out[131072 + i] = f2bf(Wv[i]);
    out[196608 + i] = f2bf(Wp[i]);
}

// ---------------------------------------------------------------------------
// PE folded into per-window-position bias: qpe[p][c] = bq[c] + sum_k pe[p][k]*Wq[c][k]
// (pe identical for every window; (x+pe)W^T = xW^T + peW^T). fp32 math.
__global__ __launch_bounds__(256) void pe_bias(
    const float* __restrict__ Wq, const float* __restrict__ bq,
    const float* __restrict__ Wk, const float* __restrict__ bk,
    float* __restrict__ qpe, float* __restrict__ kpe)
{
    __shared__ float per[256];
    const int p = blockIdx.x;       // window position 0..63
    const int c = threadIdx.x;      // channel 0..255
    const int j = p & 7, i = p >> 3;  // (x,y) coords in window
    // channels 0-63: sin(3.14*x*f/200), 64-127: cos(x), 128-191: sin(y), 192-255: cos(y)
    const float v = (c < 128) ? (float)j : (float)i;
    const float ang = 3.14f * v * (float)(c & 63) * 0.005f;
    per[c] = (c & 64) ? __cosf(ang) : __sinf(ang);
    __syncthreads();

    float aq = bq[c], ak = bk[c];
    const float* wq = Wq + (size_t)c * 256;
    const float* wk = Wk + (size_t)c * 256;
    #pragma unroll 8
    for (int k = 0; k < 256; ++k) {
        const float pv = per[k];
        aq += pv * wq[k];
        ak += pv * wk[k];
    }
    qpe[p * 256 + c] = aq;
    kpe[p * 256 + c] = ak;
}

// ---------------------------------------------------------------------------
// Fully fused per-window kernel: 1 block (512 thr, 8 waves) per window.
// Phases: stage x->LDS(bf16) | V gemm (vT in LDS) | QK gemm (q,k in LDS) |
//         attention (P via LDS roundtrip) | o->LDS | out = o@Wp^T + bp.
// All intermediates LDS-resident; weights read from L2 as B-frags.
#define STRX 264   // xs/qs/ks/os leading stride (ushort); 264*2=528B -> conflict-free b128
#define STRV 72    // vs / P stride

__global__ __launch_bounds__(512, 2) void fused_attn(
    const float* __restrict__ x,
    const unsigned short* __restrict__ Wall,   // [q|k|v|p] bf16, 65536 each
    const float* __restrict__ bv,
    const float* __restrict__ qpe,             // [64][256] fp32
    const float* __restrict__ kpe,
    const float* __restrict__ bp,
    float* __restrict__ out)
{
    __shared__ unsigned short sm[69120];       // 138240 B
    unsigned short* xs = sm;                   // [64][264]
    unsigned short* qs = sm + 16896;           // [64][264]
    unsigned short* ks = sm + 33792;           // [64][264]
    unsigned short* vs = sm + 50688;           // [256][72]  (vT: [c][tok])
    // overlays (after the regions they cover are dead):
    // P: per-wave 64x72 at sm + w*4608 (spans xs+qs+ks[0..6k])
    // os: [64][264] at sm + 50688 (over vs)

    const int tid  = threadIdx.x;
    const int w    = tid >> 6;      // wave 0..7
    const int lane = tid & 63;
    const int quad = lane >> 4;
    const int l15  = lane & 15;

    const int g = blockIdx.x;                  // window 0..2047
    const int b = g >> 8, wy = (g >> 4) & 15, wx = g & 15;
    const int rowbase = b * 16384 + wy * 1024 + wx * 8;

    const f32x4 zero4 = {0.f, 0.f, 0.f, 0.f};

    // ---- Phase 0: stage x window as bf16 into xs -------------------------
    {
        const int tk = tid >> 3;               // token in window 0..63
        const int c0 = (tid & 7) * 32;
        const int gr = rowbase + (tk >> 3) * 128 + (tk & 7);
        const float* xr = x + (size_t)gr * 256 + c0;
        #pragma unroll
        for (int i = 0; i < 32; i += 8) {
            float4 f0 = *(const float4*)(xr + i);
            float4 f1 = *(const float4*)(xr + i + 4);
            alignas(16) unsigned short st[8] = {
                f2bf(f0.x), f2bf(f0.y), f2bf(f0.z), f2bf(f0.w),
                f2bf(f1.x), f2bf(f1.y), f2bf(f1.z), f2bf(f1.w)};
            *(uint4*)&xs[tk * STRX + c0 + i] = *(const uint4*)st;
        }
    }
    __syncthreads();

    // ---- Phase 1: vT[c][tok] = Wv[c]·x[tok] + bv[c] ----------------------
    {
        const unsigned short* Wv = Wall + 131072;
        f32x4 acc[2][4];
        #pragma unroll
        for (int i = 0; i < 2; ++i)
            #pragma unroll
            for (int j = 0; j < 4; ++j) acc[i][j] = zero4;
        #pragma unroll 2
        for (int k0 = 0; k0 < 256; k0 += 32) {
            bf16x8 a[2], bb[4];
            #pragma unroll
            for (int i = 0; i < 2; ++i)
                a[i] = *(const bf16x8*)&Wv[(size_t)(w * 32 + i * 16 + l15) * 256 + k0 + quad * 8];
            #pragma unroll
            for (int j = 0; j < 4; ++j)
                bb[j] = *(const bf16x8*)&xs[(j * 16 + l15) * STRX + k0 + quad * 8];
            #pragma unroll
            for (int i = 0; i < 2; ++i)
                #pragma unroll
                for (int j = 0; j < 4; ++j)
                    acc[i][j] = MFMA16(a[i], bb[j], acc[i][j]);
        }
        #pragma unroll
        for (int i = 0; i < 2; ++i) {
            #pragma unroll
            for (int r = 0; r < 4; ++r) {
                const int c = w * 32 + i * 16 + quad * 4 + r;
                const float bbv = bv[c];
                #pragma unroll
                for (int j = 0; j < 4; ++j)
                    vs[c * STRV + j * 16 + l15] = f2bf(acc[i][j][r] + bbv);
            }
        }
    }
    __syncthreads();

    // ---- Phase 2: q,k gemms (shared A-frags from xs) ---------------------
    {
        const unsigned short* Wq = Wall;
        const unsigned short* Wk = Wall + 65536;
        f32x4 aq[4][2], ak[4][2];
        #pragma unroll
        for (int i = 0; i < 4; ++i)
            #pragma unroll
            for (int j = 0; j < 2; ++j) { aq[i][j] = zero4; ak[i][j] = zero4; }
        #pragma unroll 2
        for (int k0 = 0; k0 < 256; k0 += 32) {
            bf16x8 af[4], bq[2], bk[2];
            #pragma unroll
            for (int i = 0; i < 4; ++i)
                af[i] = *(const bf16x8*)&xs[(i * 16 + l15) * STRX + k0 + quad * 8];
            #pragma unroll
            for (int j = 0; j < 2; ++j) {
                bq[j] = *(const bf16x8*)&Wq[(size_t)(w * 32 + j * 16 + l15) * 256 + k0 + quad * 8];
                bk[j] = *(const bf16x8*)&Wk[(size_t)(w * 32 + j * 16 + l15) * 256 + k0 + quad * 8];
            }
            #pragma unroll
            for (int i = 0; i < 4; ++i)
                #pragma unroll
                for (int j = 0; j < 2; ++j) {
                    aq[i][j] = MFMA16(af[i], bq[j], aq[i][j]);
                    ak[i][j] = MFMA16(af[i], bk[j], ak[i][j]);
                }
        }
        #pragma unroll
        for (int i = 0; i < 4; ++i) {
            #pragma unroll
            for (int r = 0; r < 4; ++r) {
                const int m = i * 16 + quad * 4 + r;
                #pragma unroll
                for (int j = 0; j < 2; ++j) {
                    const int n = w * 32 + j * 16 + l15;
                    qs[m * STRX + n] = f2bf(aq[i][j][r] + qpe[m * 256 + n]);
                    ks[m * STRX + n] = f2bf(ak[i][j][r] + kpe[m * 256 + n]);
                }
            }
        }
    }
    __syncthreads();

    // ---- Phase 3: attention, wave w = head w -----------------------------
    f32x4 oa[4][2];
    {
        bf16x8 fq[4], fk[4];
        #pragma unroll
        for (int t = 0; t < 4; ++t) {
            fq[t] = *(const bf16x8*)&qs[(t * 16 + l15) * STRX + w * 32 + quad * 8];
            fk[t] = *(const bf16x8*)&ks[(t * 16 + l15) * STRX + w * 32 + quad * 8];
        }
        f32x4 s[4][4];
        #pragma unroll
        for (int mt = 0; mt < 4; ++mt)
            #pragma unroll
            for (int nt = 0; nt < 4; ++nt)
                s[mt][nt] = MFMA16(fq[mt], fk[nt], zero4);
        __syncthreads();   // all q/k frag reads done; P may now overwrite xs/qs/ks

        unsigned short* Pw = sm + w * 4608;    // 64x72 per wave
        const float KF = 0.17677669529663687f * 1.4426950408889634f;  // scale*log2e
        #pragma unroll
        for (int mt = 0; mt < 4; ++mt) {
            #pragma unroll
            for (int r = 0; r < 4; ++r) {
                float mx = fmaxf(fmaxf(s[mt][0][r], s[mt][1][r]), fmaxf(s[mt][2][r], s[mt][3][r]));
                #pragma unroll
                for (int off = 1; off < 16; off <<= 1) mx = fmaxf(mx, __shfl_xor(mx, off, 16));
                float e[4];
                float sum = 0.f;
                #pragma unroll
                for (int nt = 0; nt < 4; ++nt) { e[nt] = exp2f((s[mt][nt][r] - mx) * KF); sum += e[nt]; }
                #pragma unroll
                for (int off = 1; off < 16; off <<= 1) sum += __shfl_xor(sum, off, 16);
                const float inv = 1.0f / sum;
                const int row = mt * 16 + quad * 4 + r;
                #pragma unroll
                for (int nt = 0; nt < 4; ++nt)
                    Pw[row * STRV + nt * 16 + l15] = f2bf(e[nt] * inv);
            }
        }

        // PV: A = P (own wave's LDS region), B = vs rows c (k=tok contiguous)
        #pragma unroll
        for (int mt = 0; mt < 4; ++mt) { oa[mt][0] = zero4; oa[mt][1] = zero4; }
        #pragma unroll
        for (int kt = 0; kt < 2; ++kt) {
            bf16x8 ap[4], bvf[2];
            #pragma unroll
            for (int mt = 0; mt < 4; ++mt)
                ap[mt] = *(const bf16x8*)&Pw[(mt * 16 + l15) * STRV + kt * 32 + quad * 8];
            #pragma unroll
            for (int nv = 0; nv < 2; ++nv)
                bvf[nv] = *(const bf16x8*)&vs[(w * 32 + nv * 16 + l15) * STRV + kt * 32 + quad * 8];
            #pragma unroll
            for (int mt = 0; mt < 4; ++mt)
                #pragma unroll
                for (int nv = 0; nv < 2; ++nv)
                    oa[mt][nv] = MFMA16(ap[mt], bvf[nv], oa[mt][nv]);
        }
    }
    __syncthreads();   // all PV reads of vs done; os may overwrite vs

    // ---- Phase 4: o -> LDS (A-layout for final gemm) ---------------------
    {
        unsigned short* os = sm + 50688;
        #pragma unroll
        for (int mt = 0; mt < 4; ++mt) {
            #pragma unroll
            for (int r = 0; r < 4; ++r) {
                const int m = mt * 16 + quad * 4 + r;
                #pragma unroll
                for (int nv = 0; nv < 2; ++nv)
                    os[m * STRX + w * 32 + nv * 16 + l15] = f2bf(oa[mt][nv][r]);
            }
        }
    }
    __syncthreads();

    // ---- Phase 5: out = o @ Wp^T + bp (fp32 to global) -------------------
    {
        const unsigned short* os = sm + 50688;
        const unsigned short* Wp = Wall + 196608;
        f32x4 ac[4][2];
        #pragma unroll
        for (int i = 0; i < 4; ++i) { ac[i][0] = zero4; ac[i][1] = zero4; }
        #pragma unroll 2
        for (int k0 = 0; k0 < 256; k0 += 32) {
            bf16x8 af[4], bb[2];
            #pragma unroll
            for (int i = 0; i < 4; ++i)
                af[i] = *(const bf16x8*)&os[(i * 16 + l15) * STRX + k0 + quad * 8];
            #pragma unroll
            for (int j = 0; j < 2; ++j)
                bb[j] = *(const bf16x8*)&Wp[(size_t)(w * 32 + j * 16 + l15) * 256 + k0 + quad * 8];
            #pragma unroll
            for (int i = 0; i < 4; ++i)
                #pragma unroll
                for (int j = 0; j < 2; ++j)
                    ac[i][j] = MFMA16(af[i], bb[j], ac[i][j]);
        }
        #pragma unroll
        for (int j = 0; j < 2; ++j) {
            const int n = w * 32 + j * 16 + l15;
            const float bbp = bp[n];
            #pragma unroll
            for (int i = 0; i < 4; ++i) {
                #pragma unroll
                for (int r = 0; r < 4; ++r) {
                    const int m = i * 16 + quad * 4 + r;
                    const int gr = rowbase + (m >> 3) * 128 + (m & 7);
                    out[(size_t)gr * 256 + n] = ac[i][j][r] + bbp;
                }
            }
        }
    }
}

// ---------------------------------------------------------------------------
extern "C" void kernel_launch(void* const* d_in, const int* in_sizes, int n_in,
                              void* d_out, int out_size, void* d_ws, size_t ws_size,
                              hipStream_t stream) {
    const float* x  = (const float*)d_in[0];
    const float* Wq = (const float*)d_in[1];
    const float* bq = (const float*)d_in[2];
    const float* Wk = (const float*)d_in[3];
    const float* bk = (const float*)d_in[4];
    const float* Wv = (const float*)d_in[5];
    const float* bv = (const float*)d_in[6];
    const float* Wp = (const float*)d_in[7];
    const float* bp = (const float*)d_in[8];
    float* out = (float*)d_out;

    char* ws = (char*)d_ws;
    unsigned short* Wbf = (unsigned short*)ws;          // 4 * 65536 bf16 = 512 KB
    float* qpe = (float*)(ws + 524288);                 // 64*256 fp32 = 64 KB
    float* kpe = (float*)(ws + 524288 + 65536);         // 64 KB

    cvt_weights<<<256, 256, 0, stream>>>(Wq, Wk, Wv, Wp, Wbf);
    pe_bias<<<64, 256, 0, stream>>>(Wq, bq, Wk, bk, qpe, kpe);
    fused_attn<<<2048, 512, 0, stream>>>(x, Wbf, bv, qpe, kpe, bp, out);
}

// Round 3
// 385.096 us; speedup vs baseline: 1.3838x; 1.2028x over previous
//
#include <hip/hip_runtime.h>

typedef __bf16 bf16x8 __attribute__((ext_vector_type(8)));
typedef float f32x4 __attribute__((ext_vector_type(4)));

#define MFMA16(a, b, c) __builtin_amdgcn_mfma_f32_16x16x32_bf16((a), (b), (c), 0, 0, 0)
// wave-synchronous LDS ordering: drain DS queue, forbid compiler reordering
#define LDS_FENCE() __asm__ volatile("s_waitcnt lgkmcnt(0)" ::: "memory")

__device__ __forceinline__ unsigned short f2bf(float f) {
    union { float f; unsigned int u; } v;
    v.f = f;
    unsigned int r = v.u + 0x7fffu + ((v.u >> 16) & 1u);
    return (unsigned short)(r >> 16);
}

// ---------------------------------------------------------------------------
// Convert the four 256x256 fp32 weight matrices to bf16 (q,k,v,p contiguous).
__global__ __launch_bounds__(256) void cvt_weights(
    const float* __restrict__ Wq, const float* __restrict__ Wk,
    const float* __restrict__ Wv, const float* __restrict__ Wp,
    unsigned short* __restrict__ out)
{
    int i = blockIdx.x * 256 + threadIdx.x;  // 0..65535
    out[i]          = f2bf(Wq[i]);
    out[65536 + i]  = f2bf(Wk[i]);
    out[131072 + i] = f2bf(Wv[i]);
    out[196608 + i] = f2bf(Wp[i]);
}

// ---------------------------------------------------------------------------
// PE folded into per-window-position bias: qpe[p][c] = bq[c] + sum_k pe[p][k]*Wq[c][k]
// Coalescing fix vs R2: c is wave-uniform (weight row reads scalarize to s_load);
// PE table lives in padded LDS (8 coords -> 8 distinct banks, broadcast within).
__global__ __launch_bounds__(256) void pe_bias(
    const float* __restrict__ Wq, const float* __restrict__ bq,
    const float* __restrict__ Wk, const float* __restrict__ bk,
    float* __restrict__ qpe, float* __restrict__ kpe)
{
    __shared__ float pet[8 * 260];
    const int tid = threadIdx.x;
    for (int i = tid; i < 8 * 256; i += 256) {
        int v = i >> 8, k = i & 255;
        float ang = 3.14f * (float)v * (float)(k & 63) * 0.005f;
        pet[v * 260 + k] = (k & 64) ? __cosf(ang) : __sinf(ang);
    }
    __syncthreads();

    const int p = tid & 63;                      // window position
    const int c = blockIdx.x * 4 + (tid >> 6);   // channel (wave-uniform)
    const int jx = p & 7, iy = p >> 3;
    const float* rq = Wq + (size_t)c * 256;
    const float* rk = Wk + (size_t)c * 256;
    const float* pl = pet + jx * 260;  // k < 128 uses x-coord
    const float* ph = pet + iy * 260;  // k >= 128 uses y-coord
    float aq = bq[c], ak = bk[c];
    #pragma unroll 8
    for (int k = 0; k < 128; ++k) { float pv = pl[k]; aq += pv * rq[k]; ak += pv * rk[k]; }
    #pragma unroll 8
    for (int k = 128; k < 256; ++k) { float pv = ph[k]; aq += pv * rq[k]; ak += pv * rk[k]; }
    qpe[p * 256 + c] = aq;
    kpe[p * 256 + c] = ak;
}

// ---------------------------------------------------------------------------
// Fused per-window kernel, 76 KB LDS -> 2 blocks/CU (16 waves).
// Wave w owns head w end-to-end; cross-wave LDS = xs and os only.
// Region A (40960 B): xs[64][264] (P0-P2), then per-wave 64x40 scratch (P3).
// Region B (36864 B): vs[256][72] (P1-PV), then os[64][264] (P4-P5).
#define STRX 264
#define STRV 72
#define STRS 40

__global__ __launch_bounds__(512, 4) void fused_attn(
    const float* __restrict__ x,
    const unsigned short* __restrict__ Wall,   // [q|k|v|p] bf16, 65536 each
    const float* __restrict__ bv,
    const float* __restrict__ qpe,             // [64][256] fp32
    const float* __restrict__ kpe,
    const float* __restrict__ bp,
    float* __restrict__ out)
{
    __shared__ unsigned short sm[38912];       // 77824 B
    unsigned short* xs = sm;                   // [64][264]
    unsigned short* vs = sm + 20480;           // [256][72]
    unsigned short* os = sm + 20480;           // [64][264] overlays vs

    const int tid  = threadIdx.x;
    const int w    = tid >> 6;      // wave 0..7 == head
    const int lane = tid & 63;
    const int quad = lane >> 4;
    const int l15  = lane & 15;
    unsigned short* scr = sm + w * 2560;       // per-wave 64x40 (overlays xs)

    const int g = blockIdx.x;                  // window 0..2047
    const int b = g >> 8, wy = (g >> 4) & 15, wx = g & 15;
    const int rowbase = b * 16384 + wy * 1024 + wx * 8;

    const f32x4 zero4 = {0.f, 0.f, 0.f, 0.f};

    // ---- P0: stage x window as bf16 into xs ------------------------------
    {
        const int tk = tid >> 3;               // token 0..63
        const int c0 = (tid & 7) * 32;
        const int gr = rowbase + (tk >> 3) * 128 + (tk & 7);
        const float* xr = x + (size_t)gr * 256 + c0;
        #pragma unroll
        for (int i = 0; i < 32; i += 8) {
            float4 f0 = *(const float4*)(xr + i);
            float4 f1 = *(const float4*)(xr + i + 4);
            alignas(16) unsigned short st[8] = {
                f2bf(f0.x), f2bf(f0.y), f2bf(f0.z), f2bf(f0.w),
                f2bf(f1.x), f2bf(f1.y), f2bf(f1.z), f2bf(f1.w)};
            *(uint4*)&xs[tk * STRX + c0 + i] = *(const uint4*)st;
        }
    }
    __syncthreads();

    // ---- P1: vT[c][tok] = Wv[c]·x[tok] + bv[c] (own 32 channels) ---------
    {
        const unsigned short* Wv = Wall + 131072;
        f32x4 acc[2][4];
        #pragma unroll
        for (int i = 0; i < 2; ++i)
            #pragma unroll
            for (int j = 0; j < 4; ++j) acc[i][j] = zero4;
        #pragma unroll 2
        for (int k0 = 0; k0 < 256; k0 += 32) {
            bf16x8 a[2], bb[4];
            #pragma unroll
            for (int i = 0; i < 2; ++i)
                a[i] = *(const bf16x8*)&Wv[(size_t)(w * 32 + i * 16 + l15) * 256 + k0 + quad * 8];
            #pragma unroll
            for (int j = 0; j < 4; ++j)
                bb[j] = *(const bf16x8*)&xs[(j * 16 + l15) * STRX + k0 + quad * 8];
            #pragma unroll
            for (int i = 0; i < 2; ++i)
                #pragma unroll
                for (int j = 0; j < 4; ++j)
                    acc[i][j] = MFMA16(a[i], bb[j], acc[i][j]);
        }
        #pragma unroll
        for (int i = 0; i < 2; ++i) {
            #pragma unroll
            for (int r = 0; r < 4; ++r) {
                const int c = w * 32 + i * 16 + quad * 4 + r;
                const float bbv = bv[c];
                #pragma unroll
                for (int j = 0; j < 4; ++j)
                    vs[c * STRV + j * 16 + l15] = f2bf(acc[i][j][r] + bbv);
            }
        }
    }
    // no barrier: P2 reads xs (still valid), vs rows are wave-private

    // ---- P2: q,k gemm for head w (results stay in registers) -------------
    f32x4 aq[4][2], ak[4][2];
    {
        const unsigned short* Wq = Wall;
        const unsigned short* Wk = Wall + 65536;
        #pragma unroll
        for (int i = 0; i < 4; ++i)
            #pragma unroll
            for (int j = 0; j < 2; ++j) { aq[i][j] = zero4; ak[i][j] = zero4; }
        #pragma unroll 2
        for (int k0 = 0; k0 < 256; k0 += 32) {
            bf16x8 af[4], bq[2], bk[2];
            #pragma unroll
            for (int i = 0; i < 4; ++i)
                af[i] = *(const bf16x8*)&xs[(i * 16 + l15) * STRX + k0 + quad * 8];
            #pragma unroll
            for (int j = 0; j < 2; ++j) {
                bq[j] = *(const bf16x8*)&Wq[(size_t)(w * 32 + j * 16 + l15) * 256 + k0 + quad * 8];
                bk[j] = *(const bf16x8*)&Wk[(size_t)(w * 32 + j * 16 + l15) * 256 + k0 + quad * 8];
            }
            #pragma unroll
            for (int i = 0; i < 4; ++i)
                #pragma unroll
                for (int j = 0; j < 2; ++j) {
                    aq[i][j] = MFMA16(af[i], bq[j], aq[i][j]);
                    ak[i][j] = MFMA16(af[i], bk[j], ak[i][j]);
                }
        }
    }
    __syncthreads();   // all waves done with xs -> scratch may overwrite it

    // ---- P3: attention, fully wave-private (LDS fences, no barriers) -----
    f32x4 oa[4][2];
    {
        // q: C-layout regs -> scratch [m][d] -> A-frags
        #pragma unroll
        for (int i = 0; i < 4; ++i)
            #pragma unroll
            for (int r = 0; r < 4; ++r) {
                const int m = i * 16 + quad * 4 + r;
                #pragma unroll
                for (int j = 0; j < 2; ++j) {
                    const int n = w * 32 + j * 16 + l15;
                    scr[m * STRS + j * 16 + l15] = f2bf(aq[i][j][r] + qpe[m * 256 + n]);
                }
            }
        LDS_FENCE();
        bf16x8 fq[4];
        #pragma unroll
        for (int t = 0; t < 4; ++t)
            fq[t] = *(const bf16x8*)&scr[(t * 16 + l15) * STRS + quad * 8];
        LDS_FENCE();   // fq data landed; safe to overwrite with k
        #pragma unroll
        for (int i = 0; i < 4; ++i)
            #pragma unroll
            for (int r = 0; r < 4; ++r) {
                const int m = i * 16 + quad * 4 + r;
                #pragma unroll
                for (int j = 0; j < 2; ++j) {
                    const int n = w * 32 + j * 16 + l15;
                    scr[m * STRS + j * 16 + l15] = f2bf(ak[i][j][r] + kpe[m * 256 + n]);
                }
            }
        LDS_FENCE();
        bf16x8 fk[4];
        #pragma unroll
        for (int t = 0; t < 4; ++t)
            fk[t] = *(const bf16x8*)&scr[(t * 16 + l15) * STRS + quad * 8];

        f32x4 s[4][4];
        #pragma unroll
        for (int mt = 0; mt < 4; ++mt)
            #pragma unroll
            for (int nt = 0; nt < 4; ++nt)
                s[mt][nt] = MFMA16(fq[mt], fk[nt], zero4);

        // softmax (rows: m = mt*16 + quad*4 + r); P written back into s
        const float KF = 0.17677669529663687f * 1.4426950408889634f;  // scale*log2e
        #pragma unroll
        for (int mt = 0; mt < 4; ++mt) {
            #pragma unroll
            for (int r = 0; r < 4; ++r) {
                float mx = fmaxf(fmaxf(s[mt][0][r], s[mt][1][r]), fmaxf(s[mt][2][r], s[mt][3][r]));
                #pragma unroll
                for (int off = 1; off < 16; off <<= 1) mx = fmaxf(mx, __shfl_xor(mx, off, 16));
                float e[4];
                float sum = 0.f;
                #pragma unroll
                for (int nt = 0; nt < 4; ++nt) { e[nt] = exp2f((s[mt][nt][r] - mx) * KF); sum += e[nt]; }
                #pragma unroll
                for (int off = 1; off < 16; off <<= 1) sum += __shfl_xor(sum, off, 16);
                const float inv = 1.0f / sum;
                #pragma unroll
                for (int nt = 0; nt < 4; ++nt) s[mt][nt][r] = e[nt] * inv;
            }
        }

        // PV in two K=32 chunks through the same per-wave scratch
        #pragma unroll
        for (int mt = 0; mt < 4; ++mt) { oa[mt][0] = zero4; oa[mt][1] = zero4; }
        #pragma unroll
        for (int kt = 0; kt < 2; ++kt) {
            LDS_FENCE();   // previous chunk's ap reads landed
            #pragma unroll
            for (int mt = 0; mt < 4; ++mt)
                #pragma unroll
                for (int r = 0; r < 4; ++r) {
                    const int row = mt * 16 + quad * 4 + r;
                    #pragma unroll
                    for (int nt2 = 0; nt2 < 2; ++nt2)
                        scr[row * STRS + nt2 * 16 + l15] = f2bf(s[mt][kt * 2 + nt2][r]);
                }
            LDS_FENCE();
            bf16x8 ap[4], bvf[2];
            #pragma unroll
            for (int mt = 0; mt < 4; ++mt)
                ap[mt] = *(const bf16x8*)&scr[(mt * 16 + l15) * STRS + quad * 8];
            #pragma unroll
            for (int nv = 0; nv < 2; ++nv)
                bvf[nv] = *(const bf16x8*)&vs[(w * 32 + nv * 16 + l15) * STRV + kt * 32 + quad * 8];
            #pragma unroll
            for (int mt = 0; mt < 4; ++mt)
                #pragma unroll
                for (int nv = 0; nv < 2; ++nv)
                    oa[mt][nv] = MFMA16(ap[mt], bvf[nv], oa[mt][nv]);
        }
    }
    __syncthreads();   // all PV reads of vs done -> os may overwrite region B

    // ---- P4: o -> LDS (A-layout for final gemm) --------------------------
    #pragma unroll
    for (int mt = 0; mt < 4; ++mt)
        #pragma unroll
        for (int r = 0; r < 4; ++r) {
            const int m = mt * 16 + quad * 4 + r;
            #pragma unroll
            for (int nv = 0; nv < 2; ++nv)
                os[m * STRX + w * 32 + nv * 16 + l15] = f2bf(oa[mt][nv][r]);
        }
    __syncthreads();

    // ---- P5: out = o @ Wp^T + bp (fp32 to global) ------------------------
    {
        const unsigned short* Wp = Wall + 196608;
        f32x4 ac[4][2];
        #pragma unroll
        for (int i = 0; i < 4; ++i) { ac[i][0] = zero4; ac[i][1] = zero4; }
        #pragma unroll 2
        for (int k0 = 0; k0 < 256; k0 += 32) {
            bf16x8 af[4], bb[2];
            #pragma unroll
            for (int i = 0; i < 4; ++i)
                af[i] = *(const bf16x8*)&os[(i * 16 + l15) * STRX + k0 + quad * 8];
            #pragma unroll
            for (int j = 0; j < 2; ++j)
                bb[j] = *(const bf16x8*)&Wp[(size_t)(w * 32 + j * 16 + l15) * 256 + k0 + quad * 8];
            #pragma unroll
            for (int i = 0; i < 4; ++i)
                #pragma unroll
                for (int j = 0; j < 2; ++j)
                    ac[i][j] = MFMA16(af[i], bb[j], ac[i][j]);
        }
        #pragma unroll
        for (int j = 0; j < 2; ++j) {
            const int n = w * 32 + j * 16 + l15;
            const float bbp = bp[n];
            #pragma unroll
            for (int i = 0; i < 4; ++i) {
                #pragma unroll
                for (int r = 0; r < 4; ++r) {
                    const int m = i * 16 + quad * 4 + r;
                    const int gr = rowbase + (m >> 3) * 128 + (m & 7);
                    out[(size_t)gr * 256 + n] = ac[i][j][r] + bbp;
                }
            }
        }
    }
}

// ---------------------------------------------------------------------------
extern "C" void kernel_launch(void* const* d_in, const int* in_sizes, int n_in,
                              void* d_out, int out_size, void* d_ws, size_t ws_size,
                              hipStream_t stream) {
    const float* x  = (const float*)d_in[0];
    const float* Wq = (const float*)d_in[1];
    const float* bq = (const float*)d_in[2];
    const float* Wk = (const float*)d_in[3];
    const float* bk = (const float*)d_in[4];
    const float* Wv = (const float*)d_in[5];
    const float* bv = (const float*)d_in[6];
    const float* Wp = (const float*)d_in[7];
    const float* bp = (const float*)d_in[8];
    float* out = (float*)d_out;

    char* ws = (char*)d_ws;
    unsigned short* Wbf = (unsigned short*)ws;          // 512 KB bf16 weights
    float* qpe = (float*)(ws + 524288);                 // 64 KB
    float* kpe = (float*)(ws + 524288 + 65536);         // 64 KB

    cvt_weights<<<256, 256, 0, stream>>>(Wq, Wk, Wv, Wp, Wbf);
    pe_bias<<<64, 256, 0, stream>>>(Wq, bq, Wk, bk, qpe, kpe);
    fused_attn<<<2048, 512, 0, stream>>>(x, Wbf, bv, qpe, kpe, bp, out);
}